// Round 6
// baseline (545.822 us; speedup 1.0000x reference)
//
#include <hip/hip_runtime.h>
#include <math.h>

#define NM 65536
#define NB 128
#define NU 256
#define ND 512

// ---- output layout (flat f32, reference return order) ----
constexpr size_t OUT_READ = 0;                      // [B,U]    32768
constexpr size_t OUT_MEM  = 32768;                  // [M,U]    16777216
constexpr size_t OUT_CWU  = OUT_MEM + 16777216;     // [M,B]    8388608
constexpr size_t OUT_CWLU = OUT_CWU + 8388608;      // [M,B]
constexpr size_t OUT_CWR  = OUT_CWLU + 8388608;     // [M,B]
constexpr size_t OUT_KEY  = OUT_CWR + 8388608;      // [B,U]
constexpr size_t OUT_CC   = OUT_KEY + 32768;        // [B,U]

// ---- ws layout (bytes) ----
constexpr size_t WS_KLNT   = 0;        // 32768 f32 (klnT[u][b])
constexpr size_t WS_MINENC = 131072;   // 128 u64
constexpr size_t WS_MINS   = 132096;   // 128 f32
constexpr size_t WS_ISTAR  = 132608;   // 1 u32
constexpr size_t WS_PART   = 135168;   // 512 * 16384 f32 read-partials (32 MB)

__device__ __forceinline__ unsigned fenc(float x) {
    unsigned u = __float_as_uint(x);
    return (u & 0x80000000u) ? ~u : (u | 0x80000000u);
}
__device__ __forceinline__ float fdec(unsigned e) {
    unsigned u = (e & 0x80000000u) ? (e ^ 0x80000000u) : ~e;
    return __uint_as_float(u);
}
__device__ __forceinline__ float sigm(float x) { return 1.0f / (1.0f + expf(-x)); }

// ---------------- K1: LSTM controller + normalized keys (UNCHANGED, numerics anchor) ----------------
__global__ __launch_bounds__(256) void k_lstm(
    const float* __restrict__ xin_g, const float* __restrict__ r_tm1,
    const float* __restrict__ h_tm1, const float* __restrict__ cc_tm1,
    const float* __restrict__ Wk, const float* __restrict__ Wr,
    const float* __restrict__ bias, float* __restrict__ out,
    float* __restrict__ klnT, unsigned long long* __restrict__ minenc)
{
    const int b = blockIdx.x, t = threadIdx.x;
    __shared__ float xin[ND + NU];
    __shared__ float hh[NU];
    __shared__ float red[NU];
    for (int k = t; k < ND; k += 256) xin[k] = xin_g[b * ND + k];
    xin[ND + t] = r_tm1[b * NU + t];
    hh[t] = h_tm1[b * NU + t];
    out[OUT_READ + b * NU + t] = 0.f;              // zero read region each launch
    if (b == 0 && t < NB) minenc[t] = ~0ULL;       // init argmin atomics
    __syncthreads();

    float zi = bias[t], zf = bias[NU + t], zc = bias[2 * NU + t], zo = bias[3 * NU + t];
    #pragma unroll 4
    for (int k = 0; k < ND + NU; ++k) {
        const float x = xin[k];
        const float* w = Wk + (size_t)k * (4 * NU);
        zi += x * w[t]; zf += x * w[NU + t]; zc += x * w[2 * NU + t]; zo += x * w[3 * NU + t];
    }
    #pragma unroll 4
    for (int k = 0; k < NU; ++k) {
        const float x = hh[k];
        const float* w = Wr + (size_t)k * (4 * NU);
        zi += x * w[t]; zf += x * w[NU + t]; zc += x * w[2 * NU + t]; zo += x * w[3 * NU + t];
    }
    const float gi = sigm(zi), gf = sigm(zf), gc = tanhf(zc), go = sigm(zo);
    const float cold = cc_tm1[b * NU + t];
    const float cn = __fadd_rn(__fmul_rn(gf, cold), __fmul_rn(gi, gc));
    const float hn = __fmul_rn(go, tanhf(cn));
    out[OUT_KEY + b * NU + t] = hn;
    out[OUT_CC + b * NU + t] = cn;
    red[t] = hn * hn;
    __syncthreads();
    for (int s = 128; s > 0; s >>= 1) { if (t < s) red[t] += red[t + s]; __syncthreads(); }
    const float nrm = sqrtf(fmaxf(red[0], 1e-12f));
    klnT[t * NB + b] = hn / nrm;   // transposed [u][b]
}

// ------------- K2: fused norm + cosine GEMM + batch-softmax + usage + min -------------
// 512-thread blocks, grid 512 -> 2 blocks/CU, 4 waves/SIMD (double R5's occupancy).
// A-operand in LDS (broadcast reads), B-operand (klnT, L1/L2-hot) via 4-deep register
// ring. All per-(s,b) FMA chains ascend u; norm/softmax/usage sequences token-identical
// to R5 -> bit-identical outputs.
__global__ __launch_bounds__(512, 4) void k_dot(
    const float* __restrict__ mT, const float* __restrict__ klnT,
    const float* __restrict__ cwr_t, const float* __restrict__ cwlu_t,
    const float* __restrict__ cwu_t, const float* __restrict__ wgp,
    float* __restrict__ out, unsigned long long* __restrict__ minenc)
{
    __shared__ float ms[2][8][128];   // 8 KB A-stage, double-buffered
    __shared__ float sp[32][132];     // 16.9 KB epilogue spill (one 32-slot group)
    __shared__ float rn_s[128];
    const int t = threadIdx.x, w = t >> 6, l = t & 63;
    const int tx = t & 15, ty = t >> 4;          // ty in [0,32): 4 slots each
    const int sb = blockIdx.x * 128;
    const int sl = t & 127, uh = t >> 7;         // staging: slot sl, u-pair uh

    // ---- phase 0: row norms (bit-identical: lane-l float4 + 64-lane xor tree) ----
    #pragma unroll 8
    for (int i = 0; i < 16; ++i) {
        const int s = w * 16 + i;
        const float4 mv = *(const float4*)(mT + (size_t)(sb + s) * NU + l * 4);
        float ss = mv.x * mv.x + mv.y * mv.y + mv.z * mv.z + mv.w * mv.w;
        #pragma unroll
        for (int d = 1; d < 64; d <<= 1) ss += __shfl_xor(ss, d);
        if (l == 0) rn_s[s] = sqrtf(fmaxf(ss, 1e-12f));
    }

    // ---- GEMM: dot[s][b] = sum_u m[s][u] * kln[u][b]; thread tile 4s x 8b ----
    float acc[4][8];
    #pragma unroll
    for (int i = 0; i < 4; ++i)
        #pragma unroll
        for (int j = 0; j < 8; ++j) acc[i][j] = 0.f;

    float4 kva[4], kvb[4];            // 4-deep kv prefetch ring (global, L1/L2-hot)
    #pragma unroll
    for (int u = 0; u < 4; ++u) {
        kva[u] = *(const float4*)(klnT + (size_t)u * NB + tx * 4);
        kvb[u] = *(const float4*)(klnT + (size_t)u * NB + tx * 4 + 64);
    }
    float2 gm = *(const float2*)(mT + (size_t)(sb + sl) * NU + uh * 2);

    for (int c = 0; c < 32; ++c) {
        const int cb = c & 1;
        ms[cb][uh * 2 + 0][sl] = gm.x;   // consecutive lanes -> consecutive banks
        ms[cb][uh * 2 + 1][sl] = gm.y;
        if (c < 31)
            gm = *(const float2*)(mT + (size_t)(sb + sl) * NU + (c + 1) * 8 + uh * 2);
        __syncthreads();   // W(c);B;C(c): dbuf makes one barrier/chunk sufficient
        #pragma unroll
        for (int u8 = 0; u8 < 8; ++u8) {
            const int r = u8 & 3;      // static under unroll
            const float4 sv = *(const float4*)&ms[cb][u8][ty * 4];   // 16-lane broadcast
            const float svv[4] = {sv.x, sv.y, sv.z, sv.w};
            const float kvv[8] = {kva[r].x, kva[r].y, kva[r].z, kva[r].w,
                                  kvb[r].x, kvb[r].y, kvb[r].z, kvb[r].w};
            #pragma unroll
            for (int i = 0; i < 4; ++i)
                #pragma unroll
                for (int j = 0; j < 8; ++j)
                    acc[i][j] += svv[i] * kvv[j];   // one fmac chain ascending u per (s,b)
            const int un = (c * 8 + u8 + 4) & 255;  // wrap in last chunk (unused loads)
            kva[r] = *(const float4*)(klnT + (size_t)un * NB + tx * 4);
            kvb[r] = *(const float4*)(klnT + (size_t)un * NB + tx * 4 + 64);
        }
    }

    // ---- epilogue: 4 groups of 32 slots: spill -> softmax/usage/min ----
    const float wg = sigm(wgp[0]);
    const float omw = __fsub_rn(1.f, wg);
    unsigned long long lmin0 = ~0ULL, lmin1 = ~0ULL;
    #pragma unroll
    for (int g = 0; g < 4; ++g) {
        if ((ty >> 3) == g) {          // holders of slots [32g, 32g+32) spill
            const int sl0 = (ty & 7) * 4;
            #pragma unroll
            for (int q = 0; q < 4; ++q) {
                *(float4*)&sp[sl0 + q][tx * 4] =
                    make_float4(acc[q][0], acc[q][1], acc[q][2], acc[q][3]);
                *(float4*)&sp[sl0 + q][64 + tx * 4] =
                    make_float4(acc[q][4], acc[q][5], acc[q][6], acc[q][7]);
            }
        }
        __syncthreads();
        #pragma unroll 2
        for (int i = 0; i < 4; ++i) {
            const int s = 32 * g + w * 4 + i;
            const int m = sb + s;
            const float2 dv = *(const float2*)&sp[s - 32 * g][2 * l];
            const float rnv = rn_s[s];
            const float2 wrt = ((const float2*)(cwr_t + (size_t)m * NB))[l];
            const float2 wlu = ((const float2*)(cwlu_t + (size_t)m * NB))[l];
            const float2 wut = ((const float2*)(cwu_t + (size_t)m * NB))[l];
            const float c0 = dv.x / rnv, c1 = dv.y / rnv;
            float mx = fmaxf(c0, c1);
            #pragma unroll
            for (int d = 1; d < 64; d <<= 1) mx = fmaxf(mx, __shfl_xor(mx, d));
            const float e0 = expf(c0 - mx), e1 = expf(c1 - mx);
            float sm = e0 + e1;
            #pragma unroll
            for (int d = 1; d < 64; d <<= 1) sm += __shfl_xor(sm, d);
            const float w0 = e0 / sm, w1 = e1 / sm;
            const float cww0 = __fadd_rn(__fadd_rn(__fmul_rn(wg, wrt.x), omw), wlu.x);
            const float cww1 = __fadd_rn(__fadd_rn(__fmul_rn(wg, wrt.y), omw), wlu.y);
            const float cu0 = __fadd_rn(__fadd_rn(__fmul_rn(0.95f, wut.x), w0), cww0);
            const float cu1 = __fadd_rn(__fadd_rn(__fmul_rn(0.95f, wut.y), w1), cww1);
            ((float2*)(out + OUT_CWR))[(size_t)m * 64 + l] = make_float2(w0, w1);
            ((float2*)(out + OUT_CWU))[(size_t)m * 64 + l] = make_float2(cu0, cu1);
            const unsigned long long e0u = (((unsigned long long)fenc(cu0)) << 32) | (unsigned)m;
            const unsigned long long e1u = (((unsigned long long)fenc(cu1)) << 32) | (unsigned)m;
            lmin0 = (e0u < lmin0) ? e0u : lmin0;
            lmin1 = (e1u < lmin1) ? e1u : lmin1;
        }
        __syncthreads();   // sp free for next group
    }
    atomicMin(&minenc[2 * l], lmin0);
    atomicMin(&minenc[2 * l + 1], lmin1);
}

// ---------------- K3: global argmin (first-occurrence) ----------------
__global__ void k_argmin(const unsigned long long* __restrict__ minenc,
                         float* __restrict__ mins, unsigned* __restrict__ istar)
{
    __shared__ unsigned long long red[NB];
    const int t = threadIdx.x;
    const unsigned long long e = minenc[t];
    const unsigned enc32 = (unsigned)(e >> 32);
    mins[t] = fdec(enc32);
    red[t] = (((unsigned long long)enc32) << 32) | (unsigned)t;
    __syncthreads();
    for (int s = 64; s > 0; s >>= 1) {
        if (t < s) { const unsigned long long o = red[t + s]; if (o < red[t]) red[t] = o; }
        __syncthreads();
    }
    if (t == 0) {
        const unsigned bstar = (unsigned)(red[0] & 0xFFFFFFFFu);
        istar[0] = (unsigned)(minenc[bstar] & 0xFFFFFFFFu);
    }
}

// -------- K4a: memory update + c_wlu (register-tiled: 8 slots x 4 u per thread) --------
__global__ __launch_bounds__(256, 1) void k_mem(
    const float* __restrict__ mT,
    const float* __restrict__ cwr_t, const float* __restrict__ cwlu_t,
    const float* __restrict__ wgp, const float* __restrict__ mins,
    const unsigned* __restrict__ istar_p, float* __restrict__ out)
{
    __shared__ float key[NB][NU];   // 128 KB, [b][u]
    __shared__ float cww[32][NB];   // 16 KB, one 32-slot pass
    __shared__ float minsb[NB];
    const int t = threadIdx.x, w = t >> 6, l = t & 63;
    const int u0 = l * 4;
    const int sl = t >> 3, sb = (t & 7) * 16;

    for (int i = t; i < NB * NU / 4; i += 256)
        ((float4*)key)[i] = ((const float4*)(out + OUT_KEY))[i];
    if (t < NB) minsb[t] = mins[t];

    const float wg = sigm(wgp[0]);
    const float omw = __fsub_rn(1.f, wg);
    const int istar = (int)istar_p[0];
    const int base = blockIdx.x * 256;

    // prefetch staging + m rows for pass 0
    float4 wr[4], lu[4], wu[4], pm[8];
    #pragma unroll
    for (int k = 0; k < 4; ++k) {
        const size_t row = (size_t)(base + sl) * NB + sb + 4 * k;
        wr[k] = *(const float4*)(cwr_t + row);
        lu[k] = *(const float4*)(cwlu_t + row);
        wu[k] = *(const float4*)(out + OUT_CWU + row);
    }
    #pragma unroll
    for (int j = 0; j < 8; ++j)
        pm[j] = *(const float4*)(mT + (size_t)(base + w * 8 + j) * NU + u0);
    __syncthreads();    // key/minsb staged

    for (int p = 0; p < 8; ++p) {
        const int sp = base + p * 32;
        // phase A: cww -> LDS, c_wlu -> global
        #pragma unroll
        for (int k = 0; k < 4; ++k) {
            float4 cw;
            cw.x = __fadd_rn(__fadd_rn(__fmul_rn(wg, wr[k].x), omw), lu[k].x);
            cw.y = __fadd_rn(__fadd_rn(__fmul_rn(wg, wr[k].y), omw), lu[k].y);
            cw.z = __fadd_rn(__fadd_rn(__fmul_rn(wg, wr[k].z), omw), lu[k].z);
            cw.w = __fadd_rn(__fadd_rn(__fmul_rn(wg, wr[k].w), omw), lu[k].w);
            *(float4*)&cww[sl][sb + 4 * k] = cw;
            const float4 mb = *(const float4*)&minsb[sb + 4 * k];
            float4 wl;
            wl.x = (wu[k].x <= mb.x) ? 1.f : 0.f;
            wl.y = (wu[k].y <= mb.y) ? 1.f : 0.f;
            wl.z = (wu[k].z <= mb.z) ? 1.f : 0.f;
            wl.w = (wu[k].w <= mb.w) ? 1.f : 0.f;
            *(float4*)(out + OUT_CWLU + (size_t)(sp + sl) * NB + sb + 4 * k) = wl;
        }
        __syncthreads();    // cww ready
        // phase B: prefetch next pass (hidden under hot loop)
        float4 pmn[8];
        if (p < 7) {
            #pragma unroll
            for (int k = 0; k < 4; ++k) {
                const size_t row = (size_t)(sp + 32 + sl) * NB + sb + 4 * k;
                wr[k] = *(const float4*)(cwr_t + row);
                lu[k] = *(const float4*)(cwlu_t + row);
                wu[k] = *(const float4*)(out + OUT_CWU + row);
            }
            #pragma unroll
            for (int j = 0; j < 8; ++j)
                pmn[j] = *(const float4*)(mT + (size_t)(sp + 32 + w * 8 + j) * NU + u0);
        }
        // hot loop: per 4-b chunk: 12 ds_read_b128 + 128 FMA
        float4 acc[8];
        #pragma unroll
        for (int j = 0; j < 8; ++j) acc[j] = make_float4(0.f, 0.f, 0.f, 0.f);
        for (int b0 = 0; b0 < NB; b0 += 4) {
            const float4 kv0 = *(const float4*)&key[b0 + 0][u0];
            const float4 kv1 = *(const float4*)&key[b0 + 1][u0];
            const float4 kv2 = *(const float4*)&key[b0 + 2][u0];
            const float4 kv3 = *(const float4*)&key[b0 + 3][u0];
            #pragma unroll
            for (int j = 0; j < 8; ++j) {
                const float4 cw = *(const float4*)&cww[w * 8 + j][b0];
                acc[j].x += cw.x * kv0.x; acc[j].y += cw.x * kv0.y; acc[j].z += cw.x * kv0.z; acc[j].w += cw.x * kv0.w;
                acc[j].x += cw.y * kv1.x; acc[j].y += cw.y * kv1.y; acc[j].z += cw.y * kv1.z; acc[j].w += cw.y * kv1.w;
                acc[j].x += cw.z * kv2.x; acc[j].y += cw.z * kv2.y; acc[j].z += cw.z * kv2.z; acc[j].w += cw.z * kv2.w;
                acc[j].x += cw.w * kv3.x; acc[j].y += cw.w * kv3.y; acc[j].z += cw.w * kv3.z; acc[j].w += cw.w * kv3.w;
            }
        }
        // epilogue: + 128*keep*m, store
        #pragma unroll
        for (int j = 0; j < 8; ++j) {
            const int s = sp + w * 8 + j;
            const float kf = (s == istar) ? 0.f : 128.f;
            float4 o;
            o.x = acc[j].x + kf * pm[j].x;
            o.y = acc[j].y + kf * pm[j].y;
            o.z = acc[j].z + kf * pm[j].z;
            o.w = acc[j].w + kf * pm[j].w;
            *(float4*)(out + OUT_MEM + (size_t)s * NU + u0) = o;
            if (p < 7) pm[j] = pmn[j];
        }
        __syncthreads();    // cww free for next phase A
    }
}

// -------- K4b: read = c_wr.T @ m_tm1, register-tiled 8b x 8u, partials in ws --------
template <int USE_PART>
__global__ __launch_bounds__(256) void k_read(
    const float* __restrict__ mT, float* __restrict__ out, float* __restrict__ part)
{
    __shared__ float m_ch[2][8][128];
    __shared__ float cwr_ch[2][8][128];
    const int t = threadIdx.x;
    const int r = blockIdx.x, ri = r >> 1, uh = r & 1;
    const int s0 = ri * 256;
    const int b0 = (t & 15) * 8, u0 = (t >> 4) * 8;
    const int ssl = t >> 5, sul = (t & 31) * 4;

    float4 acc[8][2];
    #pragma unroll
    for (int bi = 0; bi < 8; ++bi) { acc[bi][0] = make_float4(0,0,0,0); acc[bi][1] = make_float4(0,0,0,0); }

    // prefetch chunk 0
    float4 pm = *(const float4*)(mT + (size_t)(s0 + ssl) * NU + uh * 128 + sul);
    float4 pc = *(const float4*)(out + OUT_CWR + (size_t)(s0 + ssl) * NB + sul);

    for (int c = 0; c < 32; ++c) {
        const int buf = c & 1;
        *(float4*)&m_ch[buf][ssl][sul] = pm;
        *(float4*)&cwr_ch[buf][ssl][sul] = pc;
        __syncthreads();
        if (c + 1 < 32) {   // prefetch next chunk (hidden under compute)
            const size_t sn = (size_t)(s0 + (c + 1) * 8 + ssl);
            pm = *(const float4*)(mT + sn * NU + uh * 128 + sul);
            pc = *(const float4*)(out + OUT_CWR + sn * NB + sul);
        }
        #pragma unroll
        for (int sj = 0; sj < 8; ++sj) {
            const float4 ca = *(const float4*)&cwr_ch[buf][sj][b0];
            const float4 cb = *(const float4*)&cwr_ch[buf][sj][b0 + 4];
            const float4 ma = *(const float4*)&m_ch[buf][sj][u0];
            const float4 mb = *(const float4*)&m_ch[buf][sj][u0 + 4];
            const float cwa[8] = {ca.x, ca.y, ca.z, ca.w, cb.x, cb.y, cb.z, cb.w};
            #pragma unroll
            for (int bi = 0; bi < 8; ++bi) {
                acc[bi][0].x += cwa[bi] * ma.x; acc[bi][0].y += cwa[bi] * ma.y;
                acc[bi][0].z += cwa[bi] * ma.z; acc[bi][0].w += cwa[bi] * ma.w;
                acc[bi][1].x += cwa[bi] * mb.x; acc[bi][1].y += cwa[bi] * mb.y;
                acc[bi][1].z += cwa[bi] * mb.z; acc[bi][1].w += cwa[bi] * mb.w;
            }
        }
    }

    if (USE_PART) {
        float* dst = part + (size_t)r * (128 * 128);
        #pragma unroll
        for (int bi = 0; bi < 8; ++bi) {
            *(float4*)(dst + (size_t)(b0 + bi) * 128 + u0) = acc[bi][0];
            *(float4*)(dst + (size_t)(b0 + bi) * 128 + u0 + 4) = acc[bi][1];
        }
    } else {
        #pragma unroll
        for (int bi = 0; bi < 8; ++bi) {
            const float v[8] = {acc[bi][0].x, acc[bi][0].y, acc[bi][0].z, acc[bi][0].w,
                                acc[bi][1].x, acc[bi][1].y, acc[bi][1].z, acc[bi][1].w};
            #pragma unroll
            for (int q = 0; q < 8; ++q)
                atomicAdd(out + OUT_READ + (size_t)(b0 + bi) * NU + uh * 128 + u0 + q, v[q]);
        }
    }
}

// ---------------- K5: deterministic read reduction ----------------
__global__ __launch_bounds__(256) void k_redread(const float* __restrict__ part,
                                                 float* __restrict__ out)
{
    const int b = blockIdx.x, u = threadIdx.x;
    const int uh = u >> 7, ul = u & 127;
    float s = 0.f;
    #pragma unroll 4
    for (int ri = 0; ri < 256; ++ri)
        s += part[((size_t)(ri * 2 + uh) * 128 + b) * 128 + ul];
    out[OUT_READ + b * NU + u] = s;
}

extern "C" void kernel_launch(void* const* d_in, const int* in_sizes, int n_in,
                              void* d_out, int out_size, void* d_ws, size_t ws_size,
                              hipStream_t stream)
{
    const float* inputs    = (const float*)d_in[0];
    const float* r_tm1     = (const float*)d_in[1];
    const float* m_tm1     = (const float*)d_in[2];
    const float* c_wu_tm1  = (const float*)d_in[3];
    const float* c_wlu_tm1 = (const float*)d_in[4];
    const float* c_wr_tm1  = (const float*)d_in[5];
    const float* h_tm1     = (const float*)d_in[6];
    const float* cc_tm1    = (const float*)d_in[7];
    const float* Wk        = (const float*)d_in[8];
    const float* Wr        = (const float*)d_in[9];
    const float* bias      = (const float*)d_in[10];
    const float* wgate     = (const float*)d_in[11];
    float* out = (float*)d_out;
    char* ws = (char*)d_ws;

    float* klnT = (float*)(ws + WS_KLNT);
    unsigned long long* minenc = (unsigned long long*)(ws + WS_MINENC);
    float* mins = (float*)(ws + WS_MINS);
    unsigned* istar = (unsigned*)(ws + WS_ISTAR);
    float* part = (float*)(ws + WS_PART);
    const bool use_part = ws_size >= WS_PART + (size_t)512 * 128 * 128 * 4;

    hipLaunchKernelGGL(k_lstm, dim3(128), dim3(256), 0, stream,
                       inputs, r_tm1, h_tm1, cc_tm1, Wk, Wr, bias, out, klnT, minenc);
    hipLaunchKernelGGL(k_dot, dim3(512), dim3(512), 0, stream,
                       m_tm1, klnT, c_wr_tm1, c_wlu_tm1, c_wu_tm1, wgate, out, minenc);
    hipLaunchKernelGGL(k_argmin, dim3(1), dim3(128), 0, stream, minenc, mins, istar);
    hipLaunchKernelGGL(k_mem, dim3(256), dim3(256), 0, stream,
                       m_tm1, c_wr_tm1, c_wlu_tm1, wgate, mins, istar, out);
    if (use_part) {
        hipLaunchKernelGGL((k_read<1>), dim3(512), dim3(256), 0, stream, m_tm1, out, part);
        hipLaunchKernelGGL(k_redread, dim3(128), dim3(256), 0, stream, part, out);
    } else {
        hipLaunchKernelGGL((k_read<0>), dim3(512), dim3(256), 0, stream, m_tm1, out, part);
    }
}

// Round 7
// 506.790 us; speedup vs baseline: 1.0770x; 1.0770x over previous
//
#include <hip/hip_runtime.h>
#include <math.h>

#define NM 65536
#define NB 128
#define NU 256
#define ND 512

// ---- output layout (flat f32, reference return order) ----
constexpr size_t OUT_READ = 0;                      // [B,U]    32768
constexpr size_t OUT_MEM  = 32768;                  // [M,U]    16777216
constexpr size_t OUT_CWU  = OUT_MEM + 16777216;     // [M,B]    8388608
constexpr size_t OUT_CWLU = OUT_CWU + 8388608;      // [M,B]
constexpr size_t OUT_CWR  = OUT_CWLU + 8388608;     // [M,B]
constexpr size_t OUT_KEY  = OUT_CWR + 8388608;      // [B,U]
constexpr size_t OUT_CC   = OUT_KEY + 32768;        // [B,U]

// ---- ws layout (bytes) ----
constexpr size_t WS_KLNT   = 0;        // 32768 f32 (klnT[u][b])
constexpr size_t WS_MINENC = 131072;   // 128 u64
constexpr size_t WS_MINS   = 132096;   // 128 f32
constexpr size_t WS_ISTAR  = 132608;   // 1 u32
constexpr size_t WS_PART   = 135168;   // 512 * 16384 f32 read-partials (32 MB)

__device__ __forceinline__ unsigned fenc(float x) {
    unsigned u = __float_as_uint(x);
    return (u & 0x80000000u) ? ~u : (u | 0x80000000u);
}
__device__ __forceinline__ float fdec(unsigned e) {
    unsigned u = (e & 0x80000000u) ? (e ^ 0x80000000u) : ~e;
    return __uint_as_float(u);
}
__device__ __forceinline__ float sigm(float x) { return 1.0f / (1.0f + expf(-x)); }

// ---------------- K1: LSTM controller + normalized keys (UNCHANGED, numerics anchor) ----------------
__global__ __launch_bounds__(256) void k_lstm(
    const float* __restrict__ xin_g, const float* __restrict__ r_tm1,
    const float* __restrict__ h_tm1, const float* __restrict__ cc_tm1,
    const float* __restrict__ Wk, const float* __restrict__ Wr,
    const float* __restrict__ bias, float* __restrict__ out,
    float* __restrict__ klnT, unsigned long long* __restrict__ minenc)
{
    const int b = blockIdx.x, t = threadIdx.x;
    __shared__ float xin[ND + NU];
    __shared__ float hh[NU];
    __shared__ float red[NU];
    for (int k = t; k < ND; k += 256) xin[k] = xin_g[b * ND + k];
    xin[ND + t] = r_tm1[b * NU + t];
    hh[t] = h_tm1[b * NU + t];
    out[OUT_READ + b * NU + t] = 0.f;              // zero read region each launch
    if (b == 0 && t < NB) minenc[t] = ~0ULL;       // init argmin atomics
    __syncthreads();

    float zi = bias[t], zf = bias[NU + t], zc = bias[2 * NU + t], zo = bias[3 * NU + t];
    #pragma unroll 4
    for (int k = 0; k < ND + NU; ++k) {
        const float x = xin[k];
        const float* w = Wk + (size_t)k * (4 * NU);
        zi += x * w[t]; zf += x * w[NU + t]; zc += x * w[2 * NU + t]; zo += x * w[3 * NU + t];
    }
    #pragma unroll 4
    for (int k = 0; k < NU; ++k) {
        const float x = hh[k];
        const float* w = Wr + (size_t)k * (4 * NU);
        zi += x * w[t]; zf += x * w[NU + t]; zc += x * w[2 * NU + t]; zo += x * w[3 * NU + t];
    }
    const float gi = sigm(zi), gf = sigm(zf), gc = tanhf(zc), go = sigm(zo);
    const float cold = cc_tm1[b * NU + t];
    const float cn = __fadd_rn(__fmul_rn(gf, cold), __fmul_rn(gi, gc));
    const float hn = __fmul_rn(go, tanhf(cn));
    out[OUT_KEY + b * NU + t] = hn;
    out[OUT_CC + b * NU + t] = cn;
    red[t] = hn * hn;
    __syncthreads();
    for (int s = 128; s > 0; s >>= 1) { if (t < s) red[t] += red[t + s]; __syncthreads(); }
    const float nrm = sqrtf(fmaxf(red[0], 1e-12f));
    klnT[t * NB + b] = hn / nrm;   // transposed [u][b]
}

// ------------- K2: fused norm + cosine GEMM + batch-softmax + usage + min -------------
// BARRIER-FREE main loop: all LDS traffic is wave-private (DS ops in-order per wave),
// so the compiler never emits vmcnt(0)-drain-before-s_barrier. kv chunks staged
// per-wave coalesced; m via per-lane register ring (8-lane broadcast-merged).
// Wave owns 32 slots; lane tile 4s x 16b. All per-(s,b) FMA chains ascend u;
// norm/softmax/usage/min sequences token-identical to R5 -> bit-identical outputs.
__global__ __launch_bounds__(256, 2) void k_dot(
    const float* __restrict__ mT, const float* __restrict__ klnT,
    const float* __restrict__ cwr_t, const float* __restrict__ cwlu_t,
    const float* __restrict__ cwu_t, const float* __restrict__ wgp,
    float* __restrict__ out, unsigned long long* __restrict__ minenc)
{
    __shared__ float kvs[4][8][128];   // 16 KB: per-wave kv chunk [u8][b]
    __shared__ float sp[4][8][132];    // 16.9 KB: per-wave epilogue spill (8 slots)
    __shared__ float rn_s[128];
    const int t = threadIdx.x, w = t >> 6, l = t & 63;
    const int sg = l >> 3, bg = l & 7;     // lane: 4 slots (sg), 16 b's (bg)
    const int sb = blockIdx.x * 128;
    const float* mrow = mT + (size_t)(sb + w * 32 + sg * 4) * NU;

    // ---- prologue: issue kv chunk 0 + m half 0 (latency hidden under norm phase) ----
    float4 gk[4];
    #pragma unroll
    for (int q = 0; q < 4; ++q)
        gk[q] = *(const float4*)(klnT + q * 256 + l * 4);
    float4 mm[4], mn[4];
    #pragma unroll
    for (int i = 0; i < 4; ++i)
        mm[i] = *(const float4*)(mrow + (size_t)i * NU);

    // ---- phase 0: row norms (token-identical to R5: lane-l float4 + xor tree) ----
    #pragma unroll 4
    for (int i = 0; i < 32; ++i) {
        const int s = w * 32 + i;
        const float4 mv = *(const float4*)(mT + (size_t)(sb + s) * NU + l * 4);
        float ss = mv.x * mv.x + mv.y * mv.y + mv.z * mv.z + mv.w * mv.w;
        #pragma unroll
        for (int d = 1; d < 64; d <<= 1) ss += __shfl_xor(ss, d);
        if (l == 0) rn_s[s] = sqrtf(fmaxf(ss, 1e-12f));   // wave-private write/read
    }

    // ---- GEMM: dot[s][b] = sum_u m[s][u] * kln[u][b] ----
    float acc[4][16];
    #pragma unroll
    for (int i = 0; i < 4; ++i)
        #pragma unroll
        for (int j = 0; j < 16; ++j) acc[i][j] = 0.f;

    for (int c = 0; c < 32; ++c) {
        // stage kv chunk c (wave-private; waits only counted vmcnt on gk)
        #pragma unroll
        for (int q = 0; q < 4; ++q)
            *(float4*)&kvs[w][0][l * 4 + q * 256] = gk[q];
        const int cn = (c < 31) ? c + 1 : 0;
        #pragma unroll
        for (int q = 0; q < 4; ++q)    // prefetch chunk c+1 (no barrier will drain it)
            gk[q] = *(const float4*)(klnT + (size_t)cn * 1024 + q * 256 + l * 4);
        #pragma unroll
        for (int h = 0; h < 2; ++h) {
            const int cm = (h == 0) ? c : cn;    // next m half: (c,1) or (c+1,0)
            const int hn = 1 - h;
            #pragma unroll
            for (int i = 0; i < 4; ++i)
                mn[i] = *(const float4*)(mrow + (size_t)i * NU + cm * 8 + hn * 4);
            #pragma unroll
            for (int u4 = 0; u4 < 4; ++u4) {
                const int u8 = h * 4 + u4;
                float4 kvv[4];
                #pragma unroll
                for (int k = 0; k < 4; ++k)   // b = bg*4 + k*32 (+0..3): conflict-free
                    kvv[k] = *(const float4*)&kvs[w][u8][bg * 4 + k * 32];
                #pragma unroll
                for (int i = 0; i < 4; ++i) {
                    const float sv = (u4 == 0) ? mm[i].x : (u4 == 1) ? mm[i].y
                                   : (u4 == 2) ? mm[i].z : mm[i].w;
                    #pragma unroll
                    for (int k = 0; k < 4; ++k) {
                        acc[i][k * 4 + 0] += sv * kvv[k].x;
                        acc[i][k * 4 + 1] += sv * kvv[k].y;
                        acc[i][k * 4 + 2] += sv * kvv[k].z;
                        acc[i][k * 4 + 3] += sv * kvv[k].w;
                    }
                }
            }
            #pragma unroll
            for (int i = 0; i < 4; ++i) mm[i] = mn[i];
        }
    }

    // ---- epilogue: 4 groups of 8 slots per wave (wave-private spill, no barriers) ----
    const float wg = sigm(wgp[0]);
    const float omw = __fsub_rn(1.f, wg);
    unsigned long long lmin0 = ~0ULL, lmin1 = ~0ULL;
    #pragma unroll
    for (int g = 0; g < 4; ++g) {
        if ((sg >> 1) == g) {          // holders of this group's slots spill
            const int d = sg & 1;
            #pragma unroll
            for (int i = 0; i < 4; ++i)
                #pragma unroll
                for (int k = 0; k < 4; ++k)
                    *(float4*)&sp[w][d * 4 + i][bg * 4 + k * 32] =
                        make_float4(acc[i][k * 4 + 0], acc[i][k * 4 + 1],
                                    acc[i][k * 4 + 2], acc[i][k * 4 + 3]);
        }
        #pragma unroll 2
        for (int i = 0; i < 8; ++i) {
            const int s = w * 32 + g * 8 + i;
            const int m = sb + s;
            const float2 dv = *(const float2*)&sp[w][i][2 * l];
            const float rnv = rn_s[s];
            const float2 wrt = ((const float2*)(cwr_t + (size_t)m * NB))[l];
            const float2 wlu = ((const float2*)(cwlu_t + (size_t)m * NB))[l];
            const float2 wut = ((const float2*)(cwu_t + (size_t)m * NB))[l];
            const float c0 = dv.x / rnv, c1 = dv.y / rnv;
            float mx = fmaxf(c0, c1);
            #pragma unroll
            for (int d = 1; d < 64; d <<= 1) mx = fmaxf(mx, __shfl_xor(mx, d));
            const float e0 = expf(c0 - mx), e1 = expf(c1 - mx);
            float sm = e0 + e1;
            #pragma unroll
            for (int d = 1; d < 64; d <<= 1) sm += __shfl_xor(sm, d);
            const float w0 = e0 / sm, w1 = e1 / sm;
            const float cww0 = __fadd_rn(__fadd_rn(__fmul_rn(wg, wrt.x), omw), wlu.x);
            const float cww1 = __fadd_rn(__fadd_rn(__fmul_rn(wg, wrt.y), omw), wlu.y);
            const float cu0 = __fadd_rn(__fadd_rn(__fmul_rn(0.95f, wut.x), w0), cww0);
            const float cu1 = __fadd_rn(__fadd_rn(__fmul_rn(0.95f, wut.y), w1), cww1);
            ((float2*)(out + OUT_CWR))[(size_t)m * 64 + l] = make_float2(w0, w1);
            ((float2*)(out + OUT_CWU))[(size_t)m * 64 + l] = make_float2(cu0, cu1);
            const unsigned long long e0u = (((unsigned long long)fenc(cu0)) << 32) | (unsigned)m;
            const unsigned long long e1u = (((unsigned long long)fenc(cu1)) << 32) | (unsigned)m;
            lmin0 = (e0u < lmin0) ? e0u : lmin0;
            lmin1 = (e1u < lmin1) ? e1u : lmin1;
        }
    }
    atomicMin(&minenc[2 * l], lmin0);
    atomicMin(&minenc[2 * l + 1], lmin1);
}

// ---------------- K3: global argmin (first-occurrence) ----------------
__global__ void k_argmin(const unsigned long long* __restrict__ minenc,
                         float* __restrict__ mins, unsigned* __restrict__ istar)
{
    __shared__ unsigned long long red[NB];
    const int t = threadIdx.x;
    const unsigned long long e = minenc[t];
    const unsigned enc32 = (unsigned)(e >> 32);
    mins[t] = fdec(enc32);
    red[t] = (((unsigned long long)enc32) << 32) | (unsigned)t;
    __syncthreads();
    for (int s = 64; s > 0; s >>= 1) {
        if (t < s) { const unsigned long long o = red[t + s]; if (o < red[t]) red[t] = o; }
        __syncthreads();
    }
    if (t == 0) {
        const unsigned bstar = (unsigned)(red[0] & 0xFFFFFFFFu);
        istar[0] = (unsigned)(minenc[bstar] & 0xFFFFFFFFu);
    }
}

// -------- K4a: memory update + c_wlu (register-tiled: 8 slots x 4 u per thread) --------
__global__ __launch_bounds__(256, 1) void k_mem(
    const float* __restrict__ mT,
    const float* __restrict__ cwr_t, const float* __restrict__ cwlu_t,
    const float* __restrict__ wgp, const float* __restrict__ mins,
    const unsigned* __restrict__ istar_p, float* __restrict__ out)
{
    __shared__ float key[NB][NU];   // 128 KB, [b][u]
    __shared__ float cww[32][NB];   // 16 KB, one 32-slot pass
    __shared__ float minsb[NB];
    const int t = threadIdx.x, w = t >> 6, l = t & 63;
    const int u0 = l * 4;
    const int sl = t >> 3, sb = (t & 7) * 16;

    for (int i = t; i < NB * NU / 4; i += 256)
        ((float4*)key)[i] = ((const float4*)(out + OUT_KEY))[i];
    if (t < NB) minsb[t] = mins[t];

    const float wg = sigm(wgp[0]);
    const float omw = __fsub_rn(1.f, wg);
    const int istar = (int)istar_p[0];
    const int base = blockIdx.x * 256;

    // prefetch staging + m rows for pass 0
    float4 wr[4], lu[4], wu[4], pm[8];
    #pragma unroll
    for (int k = 0; k < 4; ++k) {
        const size_t row = (size_t)(base + sl) * NB + sb + 4 * k;
        wr[k] = *(const float4*)(cwr_t + row);
        lu[k] = *(const float4*)(cwlu_t + row);
        wu[k] = *(const float4*)(out + OUT_CWU + row);
    }
    #pragma unroll
    for (int j = 0; j < 8; ++j)
        pm[j] = *(const float4*)(mT + (size_t)(base + w * 8 + j) * NU + u0);
    __syncthreads();    // key/minsb staged

    for (int p = 0; p < 8; ++p) {
        const int sp = base + p * 32;
        // phase A: cww -> LDS, c_wlu -> global
        #pragma unroll
        for (int k = 0; k < 4; ++k) {
            float4 cw;
            cw.x = __fadd_rn(__fadd_rn(__fmul_rn(wg, wr[k].x), omw), lu[k].x);
            cw.y = __fadd_rn(__fadd_rn(__fmul_rn(wg, wr[k].y), omw), lu[k].y);
            cw.z = __fadd_rn(__fadd_rn(__fmul_rn(wg, wr[k].z), omw), lu[k].z);
            cw.w = __fadd_rn(__fadd_rn(__fmul_rn(wg, wr[k].w), omw), lu[k].w);
            *(float4*)&cww[sl][sb + 4 * k] = cw;
            const float4 mb = *(const float4*)&minsb[sb + 4 * k];
            float4 wl;
            wl.x = (wu[k].x <= mb.x) ? 1.f : 0.f;
            wl.y = (wu[k].y <= mb.y) ? 1.f : 0.f;
            wl.z = (wu[k].z <= mb.z) ? 1.f : 0.f;
            wl.w = (wu[k].w <= mb.w) ? 1.f : 0.f;
            *(float4*)(out + OUT_CWLU + (size_t)(sp + sl) * NB + sb + 4 * k) = wl;
        }
        __syncthreads();    // cww ready
        // phase B: prefetch next pass (hidden under hot loop)
        float4 pmn[8];
        if (p < 7) {
            #pragma unroll
            for (int k = 0; k < 4; ++k) {
                const size_t row = (size_t)(sp + 32 + sl) * NB + sb + 4 * k;
                wr[k] = *(const float4*)(cwr_t + row);
                lu[k] = *(const float4*)(cwlu_t + row);
                wu[k] = *(const float4*)(out + OUT_CWU + row);
            }
            #pragma unroll
            for (int j = 0; j < 8; ++j)
                pmn[j] = *(const float4*)(mT + (size_t)(sp + 32 + w * 8 + j) * NU + u0);
        }
        // hot loop: per 4-b chunk: 12 ds_read_b128 + 128 FMA
        float4 acc[8];
        #pragma unroll
        for (int j = 0; j < 8; ++j) acc[j] = make_float4(0.f, 0.f, 0.f, 0.f);
        for (int b0 = 0; b0 < NB; b0 += 4) {
            const float4 kv0 = *(const float4*)&key[b0 + 0][u0];
            const float4 kv1 = *(const float4*)&key[b0 + 1][u0];
            const float4 kv2 = *(const float4*)&key[b0 + 2][u0];
            const float4 kv3 = *(const float4*)&key[b0 + 3][u0];
            #pragma unroll
            for (int j = 0; j < 8; ++j) {
                const float4 cw = *(const float4*)&cww[w * 8 + j][b0];
                acc[j].x += cw.x * kv0.x; acc[j].y += cw.x * kv0.y; acc[j].z += cw.x * kv0.z; acc[j].w += cw.x * kv0.w;
                acc[j].x += cw.y * kv1.x; acc[j].y += cw.y * kv1.y; acc[j].z += cw.y * kv1.z; acc[j].w += cw.y * kv1.w;
                acc[j].x += cw.z * kv2.x; acc[j].y += cw.z * kv2.y; acc[j].z += cw.z * kv2.z; acc[j].w += cw.z * kv2.w;
                acc[j].x += cw.w * kv3.x; acc[j].y += cw.w * kv3.y; acc[j].z += cw.w * kv3.z; acc[j].w += cw.w * kv3.w;
            }
        }
        // epilogue: + 128*keep*m, store
        #pragma unroll
        for (int j = 0; j < 8; ++j) {
            const int s = sp + w * 8 + j;
            const float kf = (s == istar) ? 0.f : 128.f;
            float4 o;
            o.x = acc[j].x + kf * pm[j].x;
            o.y = acc[j].y + kf * pm[j].y;
            o.z = acc[j].z + kf * pm[j].z;
            o.w = acc[j].w + kf * pm[j].w;
            *(float4*)(out + OUT_MEM + (size_t)s * NU + u0) = o;
            if (p < 7) pm[j] = pmn[j];
        }
        __syncthreads();    // cww free for next phase A
    }
}

// -------- K4b: read = c_wr.T @ m_tm1, register-tiled 8b x 8u, partials in ws --------
template <int USE_PART>
__global__ __launch_bounds__(256) void k_read(
    const float* __restrict__ mT, float* __restrict__ out, float* __restrict__ part)
{
    __shared__ float m_ch[2][8][128];
    __shared__ float cwr_ch[2][8][128];
    const int t = threadIdx.x;
    const int r = blockIdx.x, ri = r >> 1, uh = r & 1;
    const int s0 = ri * 256;
    const int b0 = (t & 15) * 8, u0 = (t >> 4) * 8;
    const int ssl = t >> 5, sul = (t & 31) * 4;

    float4 acc[8][2];
    #pragma unroll
    for (int bi = 0; bi < 8; ++bi) { acc[bi][0] = make_float4(0,0,0,0); acc[bi][1] = make_float4(0,0,0,0); }

    // prefetch chunk 0
    float4 pm = *(const float4*)(mT + (size_t)(s0 + ssl) * NU + uh * 128 + sul);
    float4 pc = *(const float4*)(out + OUT_CWR + (size_t)(s0 + ssl) * NB + sul);

    for (int c = 0; c < 32; ++c) {
        const int buf = c & 1;
        *(float4*)&m_ch[buf][ssl][sul] = pm;
        *(float4*)&cwr_ch[buf][ssl][sul] = pc;
        __syncthreads();
        if (c + 1 < 32) {   // prefetch next chunk (hidden under compute)
            const size_t sn = (size_t)(s0 + (c + 1) * 8 + ssl);
            pm = *(const float4*)(mT + sn * NU + uh * 128 + sul);
            pc = *(const float4*)(out + OUT_CWR + sn * NB + sul);
        }
        #pragma unroll
        for (int sj = 0; sj < 8; ++sj) {
            const float4 ca = *(const float4*)&cwr_ch[buf][sj][b0];
            const float4 cb = *(const float4*)&cwr_ch[buf][sj][b0 + 4];
            const float4 ma = *(const float4*)&m_ch[buf][sj][u0];
            const float4 mb = *(const float4*)&m_ch[buf][sj][u0 + 4];
            const float cwa[8] = {ca.x, ca.y, ca.z, ca.w, cb.x, cb.y, cb.z, cb.w};
            #pragma unroll
            for (int bi = 0; bi < 8; ++bi) {
                acc[bi][0].x += cwa[bi] * ma.x; acc[bi][0].y += cwa[bi] * ma.y;
                acc[bi][0].z += cwa[bi] * ma.z; acc[bi][0].w += cwa[bi] * ma.w;
                acc[bi][1].x += cwa[bi] * mb.x; acc[bi][1].y += cwa[bi] * mb.y;
                acc[bi][1].z += cwa[bi] * mb.z; acc[bi][1].w += cwa[bi] * mb.w;
            }
        }
    }

    if (USE_PART) {
        float* dst = part + (size_t)r * (128 * 128);
        #pragma unroll
        for (int bi = 0; bi < 8; ++bi) {
            *(float4*)(dst + (size_t)(b0 + bi) * 128 + u0) = acc[bi][0];
            *(float4*)(dst + (size_t)(b0 + bi) * 128 + u0 + 4) = acc[bi][1];
        }
    } else {
        #pragma unroll
        for (int bi = 0; bi < 8; ++bi) {
            const float v[8] = {acc[bi][0].x, acc[bi][0].y, acc[bi][0].z, acc[bi][0].w,
                                acc[bi][1].x, acc[bi][1].y, acc[bi][1].z, acc[bi][1].w};
            #pragma unroll
            for (int q = 0; q < 8; ++q)
                atomicAdd(out + OUT_READ + (size_t)(b0 + bi) * NU + uh * 128 + u0 + q, v[q]);
        }
    }
}

// ---------------- K5: deterministic read reduction ----------------
__global__ __launch_bounds__(256) void k_redread(const float* __restrict__ part,
                                                 float* __restrict__ out)
{
    const int b = blockIdx.x, u = threadIdx.x;
    const int uh = u >> 7, ul = u & 127;
    float s = 0.f;
    #pragma unroll 4
    for (int ri = 0; ri < 256; ++ri)
        s += part[((size_t)(ri * 2 + uh) * 128 + b) * 128 + ul];
    out[OUT_READ + b * NU + u] = s;
}

extern "C" void kernel_launch(void* const* d_in, const int* in_sizes, int n_in,
                              void* d_out, int out_size, void* d_ws, size_t ws_size,
                              hipStream_t stream)
{
    const float* inputs    = (const float*)d_in[0];
    const float* r_tm1     = (const float*)d_in[1];
    const float* m_tm1     = (const float*)d_in[2];
    const float* c_wu_tm1  = (const float*)d_in[3];
    const float* c_wlu_tm1 = (const float*)d_in[4];
    const float* c_wr_tm1  = (const float*)d_in[5];
    const float* h_tm1     = (const float*)d_in[6];
    const float* cc_tm1    = (const float*)d_in[7];
    const float* Wk        = (const float*)d_in[8];
    const float* Wr        = (const float*)d_in[9];
    const float* bias      = (const float*)d_in[10];
    const float* wgate     = (const float*)d_in[11];
    float* out = (float*)d_out;
    char* ws = (char*)d_ws;

    float* klnT = (float*)(ws + WS_KLNT);
    unsigned long long* minenc = (unsigned long long*)(ws + WS_MINENC);
    float* mins = (float*)(ws + WS_MINS);
    unsigned* istar = (unsigned*)(ws + WS_ISTAR);
    float* part = (float*)(ws + WS_PART);
    const bool use_part = ws_size >= WS_PART + (size_t)512 * 128 * 128 * 4;

    hipLaunchKernelGGL(k_lstm, dim3(128), dim3(256), 0, stream,
                       inputs, r_tm1, h_tm1, cc_tm1, Wk, Wr, bias, out, klnT, minenc);
    hipLaunchKernelGGL(k_dot, dim3(512), dim3(256), 0, stream,
                       m_tm1, klnT, c_wr_tm1, c_wlu_tm1, c_wu_tm1, wgate, out, minenc);
    hipLaunchKernelGGL(k_argmin, dim3(1), dim3(128), 0, stream, minenc, mins, istar);
    hipLaunchKernelGGL(k_mem, dim3(256), dim3(256), 0, stream,
                       m_tm1, c_wr_tm1, c_wlu_tm1, wgate, mins, istar, out);
    if (use_part) {
        hipLaunchKernelGGL((k_read<1>), dim3(512), dim3(256), 0, stream, m_tm1, out, part);
        hipLaunchKernelGGL(k_redread, dim3(128), dim3(256), 0, stream, part, out);
    } else {
        hipLaunchKernelGGL((k_read<0>), dim3(512), dim3(256), 0, stream, m_tm1, out, part);
    }
}

// Round 8
// 423.495 us; speedup vs baseline: 1.2889x; 1.1967x over previous
//
#include <hip/hip_runtime.h>
#include <hip/hip_bf16.h>
#include <math.h>

#define NM 65536
#define NB 128
#define NU 256
#define ND 512

// ---- output layout (flat f32, reference return order) ----
constexpr size_t OUT_READ = 0;                      // [B,U]    32768
constexpr size_t OUT_MEM  = 32768;                  // [M,U]    16777216
constexpr size_t OUT_CWU  = OUT_MEM + 16777216;     // [M,B]    8388608
constexpr size_t OUT_CWLU = OUT_CWU + 8388608;      // [M,B]
constexpr size_t OUT_CWR  = OUT_CWLU + 8388608;     // [M,B]
constexpr size_t OUT_KEY  = OUT_CWR + 8388608;      // [B,U]
constexpr size_t OUT_CC   = OUT_KEY + 32768;        // [B,U]

// ---- ws layout (bytes) ----
constexpr size_t WS_KLNT   = 0;        // 32768 f32 (klnT[u][b])
constexpr size_t WS_MINENC = 131072;   // 128 u64
constexpr size_t WS_MINS   = 132096;   // 128 f32
constexpr size_t WS_ISTAR  = 132608;   // 1 u32
constexpr size_t WS_PART   = 135168;   // 512 * 16384 f32 read-partials (32 MB)

typedef __attribute__((ext_vector_type(8))) short short8v;   // 8 bf16 (4 VGPRs)
typedef __attribute__((ext_vector_type(4))) float floatx4;

__device__ __forceinline__ unsigned fenc(float x) {
    unsigned u = __float_as_uint(x);
    return (u & 0x80000000u) ? ~u : (u | 0x80000000u);
}
__device__ __forceinline__ float fdec(unsigned e) {
    unsigned u = (e & 0x80000000u) ? (e ^ 0x80000000u) : ~e;
    return __uint_as_float(u);
}
__device__ __forceinline__ float sigm(float x) { return 1.0f / (1.0f + expf(-x)); }
__device__ __forceinline__ unsigned short f2b(float f) {
    __hip_bfloat16 h = __float2bfloat16(f);      // RNE
    return *reinterpret_cast<unsigned short*>(&h);
}

// ---------------- K1: LSTM controller + normalized keys (UNCHANGED, numerics anchor) ----------------
__global__ __launch_bounds__(256) void k_lstm(
    const float* __restrict__ xin_g, const float* __restrict__ r_tm1,
    const float* __restrict__ h_tm1, const float* __restrict__ cc_tm1,
    const float* __restrict__ Wk, const float* __restrict__ Wr,
    const float* __restrict__ bias, float* __restrict__ out,
    float* __restrict__ klnT, unsigned long long* __restrict__ minenc)
{
    const int b = blockIdx.x, t = threadIdx.x;
    __shared__ float xin[ND + NU];
    __shared__ float hh[NU];
    __shared__ float red[NU];
    for (int k = t; k < ND; k += 256) xin[k] = xin_g[b * ND + k];
    xin[ND + t] = r_tm1[b * NU + t];
    hh[t] = h_tm1[b * NU + t];
    out[OUT_READ + b * NU + t] = 0.f;              // zero read region each launch
    if (b == 0 && t < NB) minenc[t] = ~0ULL;       // init argmin atomics
    __syncthreads();

    float zi = bias[t], zf = bias[NU + t], zc = bias[2 * NU + t], zo = bias[3 * NU + t];
    #pragma unroll 4
    for (int k = 0; k < ND + NU; ++k) {
        const float x = xin[k];
        const float* w = Wk + (size_t)k * (4 * NU);
        zi += x * w[t]; zf += x * w[NU + t]; zc += x * w[2 * NU + t]; zo += x * w[3 * NU + t];
    }
    #pragma unroll 4
    for (int k = 0; k < NU; ++k) {
        const float x = hh[k];
        const float* w = Wr + (size_t)k * (4 * NU);
        zi += x * w[t]; zf += x * w[NU + t]; zc += x * w[2 * NU + t]; zo += x * w[3 * NU + t];
    }
    const float gi = sigm(zi), gf = sigm(zf), gc = tanhf(zc), go = sigm(zo);
    const float cold = cc_tm1[b * NU + t];
    const float cn = __fadd_rn(__fmul_rn(gf, cold), __fmul_rn(gi, gc));
    const float hn = __fmul_rn(go, tanhf(cn));
    out[OUT_KEY + b * NU + t] = hn;
    out[OUT_CC + b * NU + t] = cn;
    red[t] = hn * hn;
    __syncthreads();
    for (int s = 128; s > 0; s >>= 1) { if (t < s) red[t] += red[t + s]; __syncthreads(); }
    const float nrm = sqrtf(fmaxf(red[0], 1e-12f));
    klnT[t * NB + b] = hn / nrm;   // transposed [u][b]
}

// ------------- K2: fused norm + cosine GEMM + batch-softmax + usage + min -------------
// EXACT R4 kernel (best measured: 181 us; bit-identical numerics path).
__global__ __launch_bounds__(256, 2) void k_dot(
    const float* __restrict__ mT, const float* __restrict__ klnT,
    const float* __restrict__ cwr_t, const float* __restrict__ cwlu_t,
    const float* __restrict__ cwu_t, const float* __restrict__ wgp,
    float* __restrict__ out, unsigned long long* __restrict__ minenc)
{
    __shared__ float smem[16384];      // 64 KB: stage tiles (32 KB), later dot tile [128][128]
    __shared__ float rn_s[128];
    const int t = threadIdx.x, w = t >> 6, l = t & 63;
    const int tx = t & 15, ty = t >> 4;
    const int b0 = tx * 8, s0 = ty * 8;
    const int sb = blockIdx.x * 128;

    // ---- phase 0: row norms (bit-identical: lane-l float4 + xor tree) ----
    #pragma unroll 4
    for (int i = 0; i < 32; ++i) {
        const int s = w * 32 + i;
        const float4 mv = *(const float4*)(mT + (size_t)(sb + s) * NU + l * 4);
        float ss = mv.x * mv.x + mv.y * mv.y + mv.z * mv.z + mv.w * mv.w;
        #pragma unroll
        for (int d = 1; d < 64; d <<= 1) ss += __shfl_xor(ss, d);
        if (l == 0) rn_s[s] = sqrtf(fmaxf(ss, 1e-12f));   // wave-private write/read
    }

    // ---- phase 1: GEMM dot[s][b] = sum_u m[s][u] * kln[u][b] ----
    const int sl = t & 127, ug = t >> 7;       // ms stage: slot sl, u-halves
    const int ku_ = t >> 4, kb = (t & 15) * 4; // kl stage

    float acc[8][8];
    #pragma unroll
    for (int i = 0; i < 8; ++i)
        #pragma unroll
        for (int j = 0; j < 8; ++j) acc[i][j] = 0.f;

    float4 gm[2], gk[2];
    #pragma unroll
    for (int i = 0; i < 2; ++i) {
        gm[i] = *(const float4*)(mT + (size_t)(sb + sl) * NU + (ug + 2 * i) * 4);
        gk[i] = *(const float4*)(klnT + (size_t)ku_ * NB + kb + i * 64);
    }
    for (int c = 0; c < 16; ++c) {
        const int mo = (c & 1) * 2048;          // ms buffer offset
        const int ko = 4096 + (c & 1) * 2048;   // kl buffer offset
        #pragma unroll
        for (int i = 0; i < 2; ++i) {
            const int uo = (ug + 2 * i) * 4;
            smem[mo + (uo + 0) * 128 + sl] = gm[i].x;
            smem[mo + (uo + 1) * 128 + sl] = gm[i].y;
            smem[mo + (uo + 2) * 128 + sl] = gm[i].z;
            smem[mo + (uo + 3) * 128 + sl] = gm[i].w;
            *(float4*)&smem[ko + ku_ * 128 + kb + i * 64] = gk[i];
        }
        __syncthreads();
        if (c < 15) {   // prefetch next chunk into registers (overlaps compute)
            const int uc = (c + 1) * 16;
            #pragma unroll
            for (int i = 0; i < 2; ++i) {
                gm[i] = *(const float4*)(mT + (size_t)(sb + sl) * NU + uc + (ug + 2 * i) * 4);
                gk[i] = *(const float4*)(klnT + (size_t)(uc + ku_) * NB + kb + i * 64);
            }
        }
        #pragma unroll 4
        for (int u = 0; u < 16; ++u) {
            const float4 sv0 = *(const float4*)&smem[mo + u * 128 + s0];
            const float4 sv1 = *(const float4*)&smem[mo + u * 128 + s0 + 4];
            const float4 kv0 = *(const float4*)&smem[ko + u * 128 + b0];
            const float4 kv1 = *(const float4*)&smem[ko + u * 128 + b0 + 4];
            const float sv[8] = {sv0.x, sv0.y, sv0.z, sv0.w, sv1.x, sv1.y, sv1.z, sv1.w};
            const float kv[8] = {kv0.x, kv0.y, kv0.z, kv0.w, kv1.x, kv1.y, kv1.z, kv1.w};
            #pragma unroll
            for (int i = 0; i < 8; ++i)
                #pragma unroll
                for (int j = 0; j < 8; ++j)
                    acc[i][j] += sv[i] * kv[j];   // single fmac chain ascending u per (s,b)
        }
        __syncthreads();
    }

    // ---- phase 2: spill dot tile to LDS (aliases stage buffers; barrier-protected) ----
    #pragma unroll
    for (int i = 0; i < 8; ++i) {
        *(float4*)&smem[(s0 + i) * 128 + b0]     = make_float4(acc[i][0], acc[i][1], acc[i][2], acc[i][3]);
        *(float4*)&smem[(s0 + i) * 128 + b0 + 4] = make_float4(acc[i][4], acc[i][5], acc[i][6], acc[i][7]);
    }
    __syncthreads();

    // ---- phase 3: per-slot softmax + usage + min (exact epilogue, lane = b-pair) ----
    const float wg = sigm(wgp[0]);
    const float omw = __fsub_rn(1.f, wg);
    unsigned long long lmin0 = ~0ULL, lmin1 = ~0ULL;
    #pragma unroll 2
    for (int i = 0; i < 32; ++i) {
        const int s = w * 32 + i;
        const int m = sb + s;
        const float2 dv = *(const float2*)&smem[s * 128 + 2 * l];
        const float rnv = rn_s[s];
        const float2 wrt = ((const float2*)(cwr_t + (size_t)m * NB))[l];
        const float2 wlu = ((const float2*)(cwlu_t + (size_t)m * NB))[l];
        const float2 wut = ((const float2*)(cwu_t + (size_t)m * NB))[l];
        const float c0 = dv.x / rnv, c1 = dv.y / rnv;
        float mx = fmaxf(c0, c1);
        #pragma unroll
        for (int d = 1; d < 64; d <<= 1) mx = fmaxf(mx, __shfl_xor(mx, d));
        const float e0 = expf(c0 - mx), e1 = expf(c1 - mx);
        float sm = e0 + e1;
        #pragma unroll
        for (int d = 1; d < 64; d <<= 1) sm += __shfl_xor(sm, d);
        const float w0 = e0 / sm, w1 = e1 / sm;
        const float cww0 = __fadd_rn(__fadd_rn(__fmul_rn(wg, wrt.x), omw), wlu.x);
        const float cww1 = __fadd_rn(__fadd_rn(__fmul_rn(wg, wrt.y), omw), wlu.y);
        const float cu0 = __fadd_rn(__fadd_rn(__fmul_rn(0.95f, wut.x), w0), cww0);
        const float cu1 = __fadd_rn(__fadd_rn(__fmul_rn(0.95f, wut.y), w1), cww1);
        ((float2*)(out + OUT_CWR))[(size_t)m * 64 + l] = make_float2(w0, w1);
        ((float2*)(out + OUT_CWU))[(size_t)m * 64 + l] = make_float2(cu0, cu1);
        const unsigned long long e0u = (((unsigned long long)fenc(cu0)) << 32) | (unsigned)m;
        const unsigned long long e1u = (((unsigned long long)fenc(cu1)) << 32) | (unsigned)m;
        lmin0 = (e0u < lmin0) ? e0u : lmin0;
        lmin1 = (e1u < lmin1) ? e1u : lmin1;
    }
    atomicMin(&minenc[2 * l], lmin0);
    atomicMin(&minenc[2 * l + 1], lmin1);
}

// ---------------- K3: global argmin (first-occurrence) ----------------
__global__ void k_argmin(const unsigned long long* __restrict__ minenc,
                         float* __restrict__ mins, unsigned* __restrict__ istar)
{
    __shared__ unsigned long long red[NB];
    const int t = threadIdx.x;
    const unsigned long long e = minenc[t];
    const unsigned enc32 = (unsigned)(e >> 32);
    mins[t] = fdec(enc32);
    red[t] = (((unsigned long long)enc32) << 32) | (unsigned)t;
    __syncthreads();
    for (int s = 64; s > 0; s >>= 1) {
        if (t < s) { const unsigned long long o = red[t + s]; if (o < red[t]) red[t] = o; }
        __syncthreads();
    }
    if (t == 0) {
        const unsigned bstar = (unsigned)(red[0] & 0xFFFFFFFFu);
        istar[0] = (unsigned)(minenc[bstar] & 0xFFFFFFFFu);
    }
}

// -------- K4a v3: memory = cww @ key (bf16 MFMA) + 128*keep*m (f32) + c_wlu --------
// 512 blocks x 256 thr, 2 blocks/CU (70 KB LDS). cww bf16 [s][b] (natural A-frag),
// keyT bf16 [u][b] per u-half (natural B-frag). mfma_f32_16x16x32_bf16; C/D mapping
// col=lane&15, row=(lane>>4)*4+reg (m89-verified). c_wlu fused in staging (exact f32).
__global__ __launch_bounds__(256, 2) void k_mem(
    const float* __restrict__ mT,
    const float* __restrict__ cwr_t, const float* __restrict__ cwlu_t,
    const float* __restrict__ wgp, const float* __restrict__ mins,
    const unsigned* __restrict__ istar_p, float* __restrict__ out)
{
    __shared__ unsigned short cwwb[128 * 136];   // [s][b] bf16, stride 136 (pad: 2-way max)
    __shared__ unsigned short keyT[128 * 136];   // [u_local][b] bf16, one u-half
    const int t = threadIdx.x, w = t >> 6, l = t & 63;
    const int sb = blockIdx.x * 128;
    const float wg = sigm(wgp[0]);
    const float omw = __fsub_rn(1.f, wg);
    const int istar = (int)istar_p[0];

    // ---- S1: cww -> bf16 LDS; c_wlu -> global (exact f32 chain) ----
    {
        const int srow = t >> 5;            // 0..7
        const int bc = (t & 31) * 4;        // 0..124 (coalesced: 2 rows/wave-load)
        for (int it = 0; it < 16; ++it) {
            const int s = it * 8 + srow;
            const size_t row = (size_t)(sb + s) * NB + bc;
            const float4 wr = *(const float4*)(cwr_t + row);
            const float4 lu = *(const float4*)(cwlu_t + row);
            const float4 wu = *(const float4*)(out + OUT_CWU + row);
            float4 cw;
            cw.x = __fadd_rn(__fadd_rn(__fmul_rn(wg, wr.x), omw), lu.x);
            cw.y = __fadd_rn(__fadd_rn(__fmul_rn(wg, wr.y), omw), lu.y);
            cw.z = __fadd_rn(__fadd_rn(__fmul_rn(wg, wr.z), omw), lu.z);
            cw.w = __fadd_rn(__fadd_rn(__fmul_rn(wg, wr.w), omw), lu.w);
            ushort4 pk;
            pk.x = f2b(cw.x); pk.y = f2b(cw.y); pk.z = f2b(cw.z); pk.w = f2b(cw.w);
            *(ushort4*)&cwwb[s * 136 + bc] = pk;
            const float4 mb = *(const float4*)(mins + bc);
            float4 wl;
            wl.x = (wu.x <= mb.x) ? 1.f : 0.f;
            wl.y = (wu.y <= mb.y) ? 1.f : 0.f;
            wl.z = (wu.z <= mb.z) ? 1.f : 0.f;
            wl.w = (wu.w <= mb.w) ? 1.f : 0.f;
            *(float4*)(out + OUT_CWLU + row) = wl;
        }
    }

    const int rk = (l >> 4) * 8;     // k-offset within 32-chunk (A/B frag)
    const int rr = l & 15;           // row (A) / col-local (B) within tile

    for (int uh = 0; uh < 2; ++uh) {
        if (uh) __syncthreads();     // all reads of keyT half-0 complete
        // ---- S2: keyT half uh: key[b][u] f32 -> bf16 LDS [u_local][b] ----
        {
            const int br = t >> 5;          // 0..7
            const int ko = (t & 31) * 4;    // u-local 0..124 (coalesced reads)
            for (int it = 0; it < 16; ++it) {
                const int b = it * 8 + br;
                const float4 kv = *(const float4*)(out + OUT_KEY + (size_t)b * NU + uh * 128 + ko);
                keyT[(ko + 0) * 136 + b] = f2b(kv.x);
                keyT[(ko + 1) * 136 + b] = f2b(kv.y);
                keyT[(ko + 2) * 136 + b] = f2b(kv.z);
                keyT[(ko + 3) * 136 + b] = f2b(kv.w);
            }
        }
        __syncthreads();

        // ---- MFMA: wave w -> s-tiles {2w, 2w+1}; 8 u-tiles; K=128 in 4 chunks ----
        floatx4 acc0[8], acc1[8];
        #pragma unroll
        for (int ut = 0; ut < 8; ++ut) {
            acc0[ut] = (floatx4){0.f, 0.f, 0.f, 0.f};
            acc1[ut] = (floatx4){0.f, 0.f, 0.f, 0.f};
        }
        #pragma unroll
        for (int kc = 0; kc < 4; ++kc) {
            const short8v a0 = *(const short8v*)&cwwb[(w * 32 + rr) * 136 + kc * 32 + rk];
            const short8v a1 = *(const short8v*)&cwwb[(w * 32 + 16 + rr) * 136 + kc * 32 + rk];
            #pragma unroll
            for (int ut = 0; ut < 8; ++ut) {
                const short8v bf = *(const short8v*)&keyT[(ut * 16 + rr) * 136 + kc * 32 + rk];
                acc0[ut] = __builtin_amdgcn_mfma_f32_16x16x32_bf16(a0, bf, acc0[ut], 0, 0, 0);
                acc1[ut] = __builtin_amdgcn_mfma_f32_16x16x32_bf16(a1, bf, acc1[ut], 0, 0, 0);
            }
        }

        // ---- epilogue: D + keep*128*m (exact f32) -> OUT_MEM ----
        #pragma unroll
        for (int ut = 0; ut < 8; ++ut) {
            const int gcol = uh * 128 + ut * 16 + rr;
            #pragma unroll
            for (int q = 0; q < 4; ++q) {
                const int grow0 = sb + w * 32 + (l >> 4) * 4 + q;
                const int grow1 = grow0 + 16;
                const float mv0 = mT[(size_t)grow0 * NU + gcol];
                const float mv1 = mT[(size_t)grow1 * NU + gcol];
                const float kf0 = (grow0 == istar) ? 0.f : 128.f;
                const float kf1 = (grow1 == istar) ? 0.f : 128.f;
                out[OUT_MEM + (size_t)grow0 * NU + gcol] = acc0[ut][q] + kf0 * mv0;
                out[OUT_MEM + (size_t)grow1 * NU + gcol] = acc1[ut][q] + kf1 * mv1;
            }
        }
    }
}

// -------- K4b: read = c_wr.T @ m_tm1, register-tiled 8b x 8u, partials in ws --------
template <int USE_PART>
__global__ __launch_bounds__(256) void k_read(
    const float* __restrict__ mT, float* __restrict__ out, float* __restrict__ part)
{
    __shared__ float m_ch[2][8][128];
    __shared__ float cwr_ch[2][8][128];
    const int t = threadIdx.x;
    const int r = blockIdx.x, ri = r >> 1, uh = r & 1;
    const int s0 = ri * 256;
    const int b0 = (t & 15) * 8, u0 = (t >> 4) * 8;
    const int ssl = t >> 5, sul = (t & 31) * 4;

    float4 acc[8][2];
    #pragma unroll
    for (int bi = 0; bi < 8; ++bi) { acc[bi][0] = make_float4(0,0,0,0); acc[bi][1] = make_float4(0,0,0,0); }

    // prefetch chunk 0
    float4 pm = *(const float4*)(mT + (size_t)(s0 + ssl) * NU + uh * 128 + sul);
    float4 pc = *(const float4*)(out + OUT_CWR + (size_t)(s0 + ssl) * NB + sul);

    for (int c = 0; c < 32; ++c) {
        const int buf = c & 1;
        *(float4*)&m_ch[buf][ssl][sul] = pm;
        *(float4*)&cwr_ch[buf][ssl][sul] = pc;
        __syncthreads();
        if (c + 1 < 32) {   // prefetch next chunk (hidden under compute)
            const size_t sn = (size_t)(s0 + (c + 1) * 8 + ssl);
            pm = *(const float4*)(mT + sn * NU + uh * 128 + sul);
            pc = *(const float4*)(out + OUT_CWR + sn * NB + sul);
        }
        #pragma unroll
        for (int sj = 0; sj < 8; ++sj) {
            const float4 ca = *(const float4*)&cwr_ch[buf][sj][b0];
            const float4 cb = *(const float4*)&cwr_ch[buf][sj][b0 + 4];
            const float4 ma = *(const float4*)&m_ch[buf][sj][u0];
            const float4 mb = *(const float4*)&m_ch[buf][sj][u0 + 4];
            const float cwa[8] = {ca.x, ca.y, ca.z, ca.w, cb.x, cb.y, cb.z, cb.w};
            #pragma unroll
            for (int bi = 0; bi < 8; ++bi) {
                acc[bi][0].x += cwa[bi] * ma.x; acc[bi][0].y += cwa[bi] * ma.y;
                acc[bi][0].z += cwa[bi] * ma.z; acc[bi][0].w += cwa[bi] * ma.w;
                acc[bi][1].x += cwa[bi] * mb.x; acc[bi][1].y += cwa[bi] * mb.y;
                acc[bi][1].z += cwa[bi] * mb.z; acc[bi][1].w += cwa[bi] * mb.w;
            }
        }
    }

    if (USE_PART) {
        float* dst = part + (size_t)r * (128 * 128);
        #pragma unroll
        for (int bi = 0; bi < 8; ++bi) {
            *(float4*)(dst + (size_t)(b0 + bi) * 128 + u0) = acc[bi][0];
            *(float4*)(dst + (size_t)(b0 + bi) * 128 + u0 + 4) = acc[bi][1];
        }
    } else {
        #pragma unroll
        for (int bi = 0; bi < 8; ++bi) {
            const float v[8] = {acc[bi][0].x, acc[bi][0].y, acc[bi][0].z, acc[bi][0].w,
                                acc[bi][1].x, acc[bi][1].y, acc[bi][1].z, acc[bi][1].w};
            #pragma unroll
            for (int q = 0; q < 8; ++q)
                atomicAdd(out + OUT_READ + (size_t)(b0 + bi) * NU + uh * 128 + u0 + q, v[q]);
        }
    }
}

// ---------------- K5: deterministic read reduction ----------------
__global__ __launch_bounds__(256) void k_redread(const float* __restrict__ part,
                                                 float* __restrict__ out)
{
    const int b = blockIdx.x, u = threadIdx.x;
    const int uh = u >> 7, ul = u & 127;
    float s = 0.f;
    #pragma unroll 4
    for (int ri = 0; ri < 256; ++ri)
        s += part[((size_t)(ri * 2 + uh) * 128 + b) * 128 + ul];
    out[OUT_READ + b * NU + u] = s;
}

extern "C" void kernel_launch(void* const* d_in, const int* in_sizes, int n_in,
                              void* d_out, int out_size, void* d_ws, size_t ws_size,
                              hipStream_t stream)
{
    const float* inputs    = (const float*)d_in[0];
    const float* r_tm1     = (const float*)d_in[1];
    const float* m_tm1     = (const float*)d_in[2];
    const float* c_wu_tm1  = (const float*)d_in[3];
    const float* c_wlu_tm1 = (const float*)d_in[4];
    const float* c_wr_tm1  = (const float*)d_in[5];
    const float* h_tm1     = (const float*)d_in[6];
    const float* cc_tm1    = (const float*)d_in[7];
    const float* Wk        = (const float*)d_in[8];
    const float* Wr        = (const float*)d_in[9];
    const float* bias      = (const float*)d_in[10];
    const float* wgate     = (const float*)d_in[11];
    float* out = (float*)d_out;
    char* ws = (char*)d_ws;

    float* klnT = (float*)(ws + WS_KLNT);
    unsigned long long* minenc = (unsigned long long*)(ws + WS_MINENC);
    float* mins = (float*)(ws + WS_MINS);
    unsigned* istar = (unsigned*)(ws + WS_ISTAR);
    float* part = (float*)(ws + WS_PART);
    const bool use_part = ws_size >= WS_PART + (size_t)512 * 128 * 128 * 4;

    hipLaunchKernelGGL(k_lstm, dim3(128), dim3(256), 0, stream,
                       inputs, r_tm1, h_tm1, cc_tm1, Wk, Wr, bias, out, klnT, minenc);
    hipLaunchKernelGGL(k_dot, dim3(512), dim3(256), 0, stream,
                       m_tm1, klnT, c_wr_tm1, c_wlu_tm1, c_wu_tm1, wgate, out, minenc);
    hipLaunchKernelGGL(k_argmin, dim3(1), dim3(128), 0, stream, minenc, mins, istar);
    hipLaunchKernelGGL(k_mem, dim3(512), dim3(256), 0, stream,
                       m_tm1, c_wr_tm1, c_wlu_tm1, wgate, mins, istar, out);
    if (use_part) {
        hipLaunchKernelGGL((k_read<1>), dim3(512), dim3(256), 0, stream, m_tm1, out, part);
        hipLaunchKernelGGL(k_redread, dim3(128), dim3(256), 0, stream, part, out);
    } else {
        hipLaunchKernelGGL((k_read<0>), dim3(512), dim3(256), 0, stream, m_tm1, out, part);
    }
}